// Round 6
// baseline (853.163 us; speedup 1.0000x reference)
//
#include <hip/hip_runtime.h>
#include <hip/hip_bf16.h>

typedef unsigned int u32;
typedef unsigned short u16;
typedef unsigned long long u64;
typedef __attribute__((ext_vector_type(8))) short bf16x8;
typedef __attribute__((ext_vector_type(4))) float f32x4;

// Problem constants
#define NWORDS 4096   // B*S
#define CC 32         // chars per word
#define EE 128        // embed dim
#define HHH 256       // hidden
#define MMW 32        // words per block (one m-tile per wave, 2 mh groups)
#define VOCABN 262

// LDS row strides
#define HS 264        // u16 stride for h arrays (fastest measured, R15/R18)
#define XPS 784       // u16 stride for xp rows (392 dw)

// Workspace layout (u16 units):
//   HH pack per dir: frag[(nt*3+g)*8+kc][lane][8] -> 16*3*8*512 = 196608 u16 (bf16 hi of Whh)
//   XP table per dir: [262][768] bf16 = embed @ Wih^T (no bias)
//   bias: per dir 1024 f32: [0..511]=bih+bhh(r,z); [512..767]=bih_n; [768..1023]=bhh_n
#define PK_HHD (16*3*8*512)                  // 196608
#define XP_OFF_U16 (2*PK_HHD)                // 393216
#define XPD (VOCABN*768)                     // 201216
#define BIAS_OFF_U16 (XP_OFF_U16 + 2*XPD)    // 795648 (byte 1591296, 4-aligned)

// fused-prep grid split
#define XP_NCH 8
#define XP_CBLK ((VOCABN + XP_NCH - 1) / XP_NCH)      // 33
#define PREP_PACK_BLKS (2*PK_HHD/256)                 // 1536
#define PREP_XP_BLKS (XP_CBLK*2)                      // 66
#define PREP_BLKS (PREP_PACK_BLKS + PREP_XP_BLKS + 1) // 1603

__device__ __forceinline__ float bf2f(u16 u){ union{u32 i; float f;} v; v.i=((u32)u)<<16; return v.f; }
__device__ __forceinline__ u16 f2bf(float f){
  __hip_bfloat16 h = __float2bfloat16(f);   // rne
  u16 r; __builtin_memcpy(&r, &h, 2); return r;
}
__device__ __forceinline__ float sigmoid_f(float x){
  float e = __builtin_amdgcn_exp2f(-1.4426950408889634f * x);
  return __builtin_amdgcn_rcpf(1.0f + e);
}
__device__ __forceinline__ float tanh_f(float x){
  float ax = __builtin_fabsf(x);
  float e  = __builtin_amdgcn_exp2f(-2.8853900817779268f * ax);
  float t  = 1.0f - 2.0f * e * __builtin_amdgcn_rcpf(1.0f + e);
  return __builtin_copysignf(t, x);
}

// ---- fused prep: Whh pack + tiled XP table + biases, one launch (R15, verbatim) ----
__global__ void prep_all(const float* __restrict__ emb,
                         const float* __restrict__ Wih_fw, const float* __restrict__ Whh_fw,
                         const float* __restrict__ bih_fw, const float* __restrict__ bhh_fw,
                         const float* __restrict__ Wih_bw, const float* __restrict__ Whh_bw,
                         const float* __restrict__ bih_bw, const float* __restrict__ bhh_bw,
                         u16* __restrict__ wsu)
{
  const int bid = blockIdx.x, tid = threadIdx.x;
  if (bid < PREP_PACK_BLKS) {
    // -------- Whh pack (bf16 hi only) --------
    int idx = bid*256 + tid;                  // 2*PK_HHD elements
    int d = idx / PK_HHD;
    int e = idx - d*PK_HHD;
    const float* Whh = d ? Whh_bw : Whh_fw;
    int jj   = e & 7;
    int lane = (e >> 3) & 63;
    int kc   = (e >> 9) & 7;
    int gnt  = e >> 12;                       // nt*3+g, < 48
    int g = gnt % 3, nt = gnt / 3;
    int row = g*256 + nt*16 + (lane & 15);
    int k   = kc*32 + ((lane >> 4) << 3) + jj;
    wsu[idx] = f2bf(Whh[row*HHH + k]);
  } else if (bid < PREP_PACK_BLKS + PREP_XP_BLKS) {
    // -------- XP table, tiled: block = (8 chars x dir), embed rows in LDS --------
    const int b    = bid - PREP_PACK_BLKS;
    const int dirb = b & 1;
    const int c0   = (b >> 1) * XP_NCH;
    const float* Wih = dirb ? Wih_bw : Wih_fw;
    u16* xpo = wsu + XP_OFF_U16 + (size_t)dirb*XPD;

    __shared__ float sh_E[XP_NCH][EE];        // 4 KB
    for (int i = tid; i < XP_NCH*EE; i += 256) {
      int c = c0 + i/EE;
      sh_E[0][i] = (c < VOCABN) ? emb[(size_t)c*EE + (i & (EE-1))] : 0.0f;
    }
    __syncthreads();

    #pragma unroll 1
    for (int q = 0; q < 3; ++q) {             // gate channel g = q*256 + tid
      const int g = q*256 + tid;
      const float* W = Wih + (size_t)g*EE;
      float acc[XP_NCH];
      #pragma unroll
      for (int c = 0; c < XP_NCH; ++c) acc[c] = 0.0f;
      #pragma unroll 2
      for (int k = 0; k < EE; k += 4) {
        float4 wv = *(const float4*)(W + k);
        #pragma unroll
        for (int c = 0; c < XP_NCH; ++c) {
          float4 ev = *(const float4*)(&sh_E[c][k]);
          acc[c] = fmaf(ev.w, wv.w, fmaf(ev.z, wv.z, fmaf(ev.y, wv.y, fmaf(ev.x, wv.x, acc[c]))));
        }
      }
      #pragma unroll
      for (int c = 0; c < XP_NCH; ++c) {
        int ci = c0 + c;
        if (ci < VOCABN) xpo[(size_t)ci*768 + g] = f2bf(acc[c]);
      }
    }
  } else {
    // -------- biases (one block handles all 2048, 8 per thread) --------
    #pragma unroll
    for (int rep = 0; rep < 8; ++rep) {
      int i = rep*256 + tid;
      int d = i >> 10, o = i & 1023;
      const float* bih = d ? bih_bw : bih_fw;
      const float* bhh = d ? bhh_bw : bhh_fw;
      float v;
      if (o < 512)      v = bih[o] + bhh[o];
      else if (o < 768) v = bih[o - 512 + 512];   // bih_n
      else              v = bhh[o - 768 + 512];   // bhh_n
      ((float*)(wsu + BIAS_OFF_U16))[d*1024 + o] = v;
    }
  }
}

// ==== R0 (287us steady) skeleton with ONE structural change: wave re-split.
//  Wave = (mh = wave>>3, nt2 = wave&7): ONE m-tile (16 words) x TWO gate-column
//  tiles (32 channels, 3 gates). A-frag (h hi/lo) LDS reads per wave per step
//  drop 32 -> 16 b128; per-CU A-read cost halves (6.1k -> 3.1k cy) -- the
//  dominant LDS line item (every wave previously re-read all 32KB of h).
//  B frags (Whh) now read by the mh=0/mh=1 wave pair -> 2nd read hits per-CU
//  L1; L2-side B traffic unchanged vs R0. B streamed with the proven 4-slot
//  rotation at half-batch (3-frag) granularity: 16 hb/step, 16%4==0 aligned.
//  Staging is R0's exact gather+ds_write (measured-best; gload_lds was -2k
//  cy/step). Register-h epilogue, ballot masks, transposed chars, nt hints
//  kept (R1/R4 verified). ~105 VGPR < 128 @ (1024,4): no pin bait, no spills
//  (tripwire: WRITE_SIZE <= 70 MB).
__global__ __launch_bounds__(1024, 4)
void gru_mfma(const int* __restrict__ chars, const int* __restrict__ chars_mask,
              const int* __restrict__ data_mask, const u16* __restrict__ wsu,
              float* __restrict__ out)
{
  const int dir   = blockIdx.x & 1;           // XCD parity: one dir per XCD
  const int word0 = (blockIdx.x >> 1) * MMW;
  const int j     = threadIdx.x;              // 0..1023 = 16 waves (4 per SIMD)
  const int wave  = j >> 6, lane = j & 63;
  const int quad  = lane >> 4, l15 = lane & 15;
  const int nt2   = wave & 7;                 // gate-column pair: channels nt2*32..+31
  const int mh    = wave >> 3;                // m-tile: words mh*16..mh*16+15

  const bf16x8* pHH  = (const bf16x8*)(wsu + (size_t)dir*PK_HHD);
  const u16*    xpt  = wsu + XP_OFF_U16 + (size_t)dir*XPD;
  const float*  bias = (const float*)(wsu + BIAS_OFF_U16) + dir*1024;

  // B-frag base for this wave's two nt tiles (nt = 2*nt2 + h):
  // frag (h,g,kc) at bA[(h*24 + g*8 + kc)*64]
  const bf16x8* bA = pHH + (size_t)(nt2*6)*8*64 + lane;

  __shared__ __align__(16) u16 sh_hhi[MMW][HS];      // bf16 hi of h (16.9 KB)
  __shared__ __align__(16) u16 sh_hlo[MMW][HS];      // bf16 lo of h (16.9 KB)
  __shared__ __align__(16) u16 sh_xp[MMW][XPS];      // xp rows (50.2 KB)
  __shared__ __align__(16) int sh_cit[CC][MMW];      // chars, transposed (4 KB)
  __shared__ u32 sh_mb[MMW];                         // per-word step-mask bits

  const int sw = j >> 5, sp = j & 31;       // xp-staging: word (32), 24-u16 part (32)

  // ---- one-time staging ----
  {
    const int w = sw, c = sp;
    sh_cit[c][w] = __builtin_nontemporal_load(&chars[(word0 + w)*CC + c]);
    int mv = __builtin_nontemporal_load(&chars_mask[(word0 + w)*CC + c]);
    u64 bal = __ballot(mv != 0);            // lanes 0..31 -> word 2*wave, 32..63 -> 2*wave+1
    if (lane == 0) {
      sh_mb[2*wave]     = (u32)bal;
      sh_mb[2*wave + 1] = (u32)(bal >> 32);
    }
  }
  for (int i = j; i < MMW*HS/2; i += 1024) { ((float*)sh_hhi)[i] = 0.0f; ((float*)sh_hlo)[i] = 0.0f; }
  __syncthreads();

  // two output channels per lane: ch0 + 0/16
  const int ch0 = nt2*32 + l15;
  float bR2[2], bZ2[2], bXN2[2], bHN2[2];
  #pragma unroll
  for (int a = 0; a < 2; ++a) {
    bR2[a]  = bias[ch0 + a*16];
    bZ2[a]  = bias[256 + ch0 + a*16];
    bXN2[a] = bias[512 + ch0 + a*16];
    bHN2[a] = bias[768 + ch0 + a*16];
  }

  // per-lane owned words: word = mh*16 + quad*4 + r  (4 words x 2 chs)
  u32 mb[4];
  float hreg[2][4];
  #pragma unroll
  for (int r = 0; r < 4; ++r) {
    mb[r] = sh_mb[mh*16 + quad*4 + r];
    hreg[0][r] = 0.0f; hreg[1][r] = 0.0f;
  }

  // B rotation: 16 half-batches/step (hb -> kc=hb>>1, nt-half=hb&1), 3 frags
  // (r,z,n) each. 4 slots, lookahead 3; 16%4==0 -> step-aligned (R18 pattern).
  bf16x8 buf[4][3];
  auto load_hb = [&](int hb, bf16x8 dst[3]) {
    const int base = (hb & 1)*24 + (hb >> 1);
    #pragma unroll
    for (int g = 0; g < 3; ++g) dst[g] = bA[(base + g*8)*64];
  };
  load_hb(0, buf[0]);
  load_hb(1, buf[1]);
  load_hb(2, buf[2]);

  #pragma unroll 1
  for (int s = 0; s < CC; ++s) {
    const int t = dir ? (CC - 1 - s) : s;
    __syncthreads();                                   // S0: h writes visible, prev xp reads done

    // ---- stage current char's xp rows (R0-exact: gather + immediate ds_write) ----
    {
      int ci = sh_cit[t][sw];
      const uint4* src = (const uint4*)(xpt + (size_t)ci*768);   // 96 uint4 per row
      uint4 a0 = src[sp*3], a1 = src[sp*3+1], a2 = src[sp*3+2];
      *(uint4*)&sh_xp[sw][sp*24]      = a0;
      *(uint4*)&sh_xp[sw][sp*24 + 8]  = a1;
      *(uint4*)&sh_xp[sw][sp*24 + 16] = a2;
    }

    // acc[g][a]: g in {r,z,hn}, a = nt-half (channel ch0 + a*16)
    f32x4 acc[3][2];
    #pragma unroll
    for (int a = 0; a < 2; ++a) {
      acc[0][a] = (f32x4){bR2[a],bR2[a],bR2[a],bR2[a]};
      acc[1][a] = (f32x4){bZ2[a],bZ2[a],bZ2[a],bZ2[a]};
      acc[2][a] = (f32x4){bHN2[a],bHN2[a],bHN2[a],bHN2[a]};
    }

    // r,z gates: h_hi only (bounded, non-compounding error). n gate: exact hi+lo.
    // A-frag (ah,al) read once per kc, shared by both nt halves.
    bf16x8 ah, al;
    #pragma unroll
    for (int b = 0; b < 16; ++b) {
      if ((b & 1) == 0) {
        const int kc = b >> 1;
        ah = *(const bf16x8*)&sh_hhi[mh*16 + l15][kc*32 + quad*8];
        al = *(const bf16x8*)&sh_hlo[mh*16 + l15][kc*32 + quad*8];
      }
      const int a = b & 1;
      acc[0][a] = __builtin_amdgcn_mfma_f32_16x16x32_bf16(ah, buf[b & 3][0], acc[0][a], 0,0,0);
      acc[1][a] = __builtin_amdgcn_mfma_f32_16x16x32_bf16(ah, buf[b & 3][1], acc[1][a], 0,0,0);
      acc[2][a] = __builtin_amdgcn_mfma_f32_16x16x32_bf16(ah, buf[b & 3][2], acc[2][a], 0,0,0);
      acc[2][a] = __builtin_amdgcn_mfma_f32_16x16x32_bf16(al, buf[b & 3][2], acc[2][a], 0,0,0);
      load_hb((b + 3) & 15, buf[(b + 3) & 3]);         // b>=13 pre-issues next step's 0,1,2
    }

    __syncthreads();                                   // S2: h frag reads + xp writes done

    // ---- gate math + h update (lane owns (word, ch) pairs; h_old in regs) ----
    #pragma unroll
    for (int a = 0; a < 2; ++a) {
      const int ch = ch0 + a*16;
      #pragma unroll
      for (int r = 0; r < 4; ++r) {
        const int word = mh*16 + quad*4 + r;
        const u16* xrow = &sh_xp[word][0];
        float xr = bf2f(xrow[ch]);
        float xz = bf2f(xrow[256 + ch]);
        float xn = bf2f(xrow[512 + ch]);
        float rr = sigmoid_f(acc[0][a][r] + xr);
        float zz = sigmoid_f(acc[1][a][r] + xz);
        float nn = tanh_f(fmaf(rr, acc[2][a][r], bXN2[a] + xn));
        float hold = hreg[a][r];
        float hnew = fmaf(zz, hold - nn, nn);                  // (1-z)*n + z*h
        float cmf  = (float)((mb[r] >> t) & 1u);
        float hm   = fmaf(cmf, hnew - hold, hold);             // mask freeze
        hreg[a][r] = hm;
        u16 hi = f2bf(hm);
        sh_hhi[word][ch] = hi;
        sh_hlo[word][ch] = f2bf(hm - bf2f(hi));
      }
    }
  }

  // ---- output straight from registers (owner mapping), nt stores ----
  #pragma unroll
  for (int r = 0; r < 4; ++r) {
    const int word = mh*16 + quad*4 + r;
    float dm = (float)__builtin_nontemporal_load(&data_mask[word0 + word]);
    #pragma unroll
    for (int a = 0; a < 2; ++a) {
      __builtin_nontemporal_store(hreg[a][r] * dm,
                                  &out[(size_t)(word0 + word)*(2*HHH) + dir*HHH + ch0 + a*16]);
    }
  }
}

extern "C" void kernel_launch(void* const* d_in, const int* in_sizes, int n_in,
                              void* d_out, int out_size, void* d_ws, size_t ws_size,
                              hipStream_t stream) {
  const int*   chars      = (const int*)d_in[0];
  const int*   chars_mask = (const int*)d_in[1];
  const int*   data_mask  = (const int*)d_in[2];
  const float* embed      = (const float*)d_in[3];
  const float* Wih_fw     = (const float*)d_in[4];
  const float* Whh_fw     = (const float*)d_in[5];
  const float* bih_fw     = (const float*)d_in[6];
  const float* bhh_fw     = (const float*)d_in[7];
  const float* Wih_bw     = (const float*)d_in[8];
  const float* Whh_bw     = (const float*)d_in[9];
  const float* bih_bw     = (const float*)d_in[10];
  const float* bhh_bw     = (const float*)d_in[11];
  u16* wsu = (u16*)d_ws;

  prep_all<<<PREP_BLKS, 256, 0, stream>>>(embed, Wih_fw, Whh_fw, bih_fw, bhh_fw,
                                          Wih_bw, Whh_bw, bih_bw, bhh_bw, wsu);

  // 256 blocks: (word-group, dir) packed so dir == blockIdx&1 (XCD parity)
  gru_mfma<<<(NWORDS/MMW)*2, 1024, 0, stream>>>(chars, chars_mask, data_mask, wsu, (float*)d_out);
}

// Round 7
// 416.511 us; speedup vs baseline: 2.0484x; 2.0484x over previous
//
#include <hip/hip_runtime.h>
#include <hip/hip_bf16.h>

typedef unsigned int u32;
typedef unsigned short u16;
typedef unsigned long long u64;
typedef __attribute__((ext_vector_type(8))) short bf16x8;
typedef __attribute__((ext_vector_type(4))) float f32x4;

// Problem constants
#define NWORDS 4096   // B*S
#define CC 32         // chars per word
#define EE 128        // embed dim
#define HHH 256       // hidden
#define MMW 32        // words per block (2 m-tiles per wave)
#define VOCABN 262

// LDS row strides
#define HS 264        // u16 stride for h arrays (fastest measured, R15/R18)
#define XPS 788       // u16 stride for xp rows. 788 = 394 dw; 4-word quad stride
                      // 1576 dw % 32 = 8 -> quads hit disjoint bank octets ->
                      // epilogue reads conflict-free (784 was a 4-way conflict)

// Workspace layout (u16 units):
//   HH pack per dir: frag[(nt*3+g)*8+kc][lane][8] -> 16*3*8*512 = 196608 u16 (bf16 hi of Whh)
//   XP table per dir: [262][768] bf16 = embed @ Wih^T (no bias)
//   bias: per dir 1024 f32: [0..511]=bih+bhh(r,z); [512..767]=bih_n; [768..1023]=bhh_n
#define PK_HHD (16*3*8*512)                  // 196608
#define XP_OFF_U16 (2*PK_HHD)                // 393216
#define XPD (VOCABN*768)                     // 201216
#define BIAS_OFF_U16 (XP_OFF_U16 + 2*XPD)    // 795648 (byte 1591296, 4-aligned)

// fused-prep grid split
#define XP_NCH 8
#define XP_CBLK ((VOCABN + XP_NCH - 1) / XP_NCH)      // 33
#define PREP_PACK_BLKS (2*PK_HHD/256)                 // 1536
#define PREP_XP_BLKS (XP_CBLK*2)                      // 66
#define PREP_BLKS (PREP_PACK_BLKS + PREP_XP_BLKS + 1) // 1603

__device__ __forceinline__ float bf2f(u16 u){ union{u32 i; float f;} v; v.i=((u32)u)<<16; return v.f; }
__device__ __forceinline__ u16 f2bf(float f){
  __hip_bfloat16 h = __float2bfloat16(f);   // rne
  u16 r; __builtin_memcpy(&r, &h, 2); return r;
}
__device__ __forceinline__ float sigmoid_f(float x){
  float e = __builtin_amdgcn_exp2f(-1.4426950408889634f * x);
  return __builtin_amdgcn_rcpf(1.0f + e);
}
__device__ __forceinline__ float tanh_f(float x){
  float ax = __builtin_fabsf(x);
  float e  = __builtin_amdgcn_exp2f(-2.8853900817779268f * ax);
  float t  = 1.0f - 2.0f * e * __builtin_amdgcn_rcpf(1.0f + e);
  return __builtin_copysignf(t, x);
}

// ---- fused prep: Whh pack + tiled XP table + biases, one launch (R15, verbatim) ----
__global__ void prep_all(const float* __restrict__ emb,
                         const float* __restrict__ Wih_fw, const float* __restrict__ Whh_fw,
                         const float* __restrict__ bih_fw, const float* __restrict__ bhh_fw,
                         const float* __restrict__ Wih_bw, const float* __restrict__ Whh_bw,
                         const float* __restrict__ bih_bw, const float* __restrict__ bhh_bw,
                         u16* __restrict__ wsu)
{
  const int bid = blockIdx.x, tid = threadIdx.x;
  if (bid < PREP_PACK_BLKS) {
    // -------- Whh pack (bf16 hi only) --------
    int idx = bid*256 + tid;                  // 2*PK_HHD elements
    int d = idx / PK_HHD;
    int e = idx - d*PK_HHD;
    const float* Whh = d ? Whh_bw : Whh_fw;
    int jj   = e & 7;
    int lane = (e >> 3) & 63;
    int kc   = (e >> 9) & 7;
    int gnt  = e >> 12;                       // nt*3+g, < 48
    int g = gnt % 3, nt = gnt / 3;
    int row = g*256 + nt*16 + (lane & 15);
    int k   = kc*32 + ((lane >> 4) << 3) + jj;
    wsu[idx] = f2bf(Whh[row*HHH + k]);
  } else if (bid < PREP_PACK_BLKS + PREP_XP_BLKS) {
    // -------- XP table, tiled: block = (8 chars x dir), embed rows in LDS --------
    const int b    = bid - PREP_PACK_BLKS;
    const int dirb = b & 1;
    const int c0   = (b >> 1) * XP_NCH;
    const float* Wih = dirb ? Wih_bw : Wih_fw;
    u16* xpo = wsu + XP_OFF_U16 + (size_t)dirb*XPD;

    __shared__ float sh_E[XP_NCH][EE];        // 4 KB
    for (int i = tid; i < XP_NCH*EE; i += 256) {
      int c = c0 + i/EE;
      sh_E[0][i] = (c < VOCABN) ? emb[(size_t)c*EE + (i & (EE-1))] : 0.0f;
    }
    __syncthreads();

    #pragma unroll 1
    for (int q = 0; q < 3; ++q) {             // gate channel g = q*256 + tid
      const int g = q*256 + tid;
      const float* W = Wih + (size_t)g*EE;
      float acc[XP_NCH];
      #pragma unroll
      for (int c = 0; c < XP_NCH; ++c) acc[c] = 0.0f;
      #pragma unroll 2
      for (int k = 0; k < EE; k += 4) {
        float4 wv = *(const float4*)(W + k);
        #pragma unroll
        for (int c = 0; c < XP_NCH; ++c) {
          float4 ev = *(const float4*)(&sh_E[c][k]);
          acc[c] = fmaf(ev.w, wv.w, fmaf(ev.z, wv.z, fmaf(ev.y, wv.y, fmaf(ev.x, wv.x, acc[c]))));
        }
      }
      #pragma unroll
      for (int c = 0; c < XP_NCH; ++c) {
        int ci = c0 + c;
        if (ci < VOCABN) xpo[(size_t)ci*768 + g] = f2bf(acc[c]);
      }
    }
  } else {
    // -------- biases (one block handles all 2048, 8 per thread) --------
    #pragma unroll
    for (int rep = 0; rep < 8; ++rep) {
      int i = rep*256 + tid;
      int d = i >> 10, o = i & 1023;
      const float* bih = d ? bih_bw : bih_fw;
      const float* bhh = d ? bhh_bw : bhh_fw;
      float v;
      if (o < 512)      v = bih[o] + bhh[o];
      else if (o < 768) v = bih[o - 512 + 512];   // bih_n
      else              v = bhh[o - 768 + 512];   // bhh_n
      ((float*)(wsu + BIAS_OFF_U16))[d*1024 + o] = v;
    }
  }
}

// ==== R0 (287us steady, measured best) VERBATIM skeleton: same wave split
// (wave = nt gate-tile, 2 m-tiles), same staging (gather + immediate ds_write,
// single sh_xp buffer), same 2 barriers, same buf[4][3] B rotation.
// Three safe deltas only:
//  1. XPS 784 -> 788: kills the structural 4-way bank conflict on the 24
//     epilogue xp reads/thread (quad stride now 8 mod 32 banks).
//  2. Epilogue LDS diet (R1/R6-verified pieces): h in hreg (lane owns
//     (word,ch) forever), ballot step-masks replace sh_cm, chars transposed,
//     output straight from registers.
//  3. nt hints on single-touch traffic (out store, chars/masks loads) to cut
//     L2 write-allocate pollution.
// __launch_bounds__(1024,4) only raises the VGPR cap (LDS already caps at
// 1 block/CU = 4 waves/EU). WRITE_SIZE <= 60 MB is the spill tripwire.
__global__ __launch_bounds__(1024, 4)
void gru_mfma(const int* __restrict__ chars, const int* __restrict__ chars_mask,
              const int* __restrict__ data_mask, const u16* __restrict__ wsu,
              float* __restrict__ out)
{
  const int dir   = blockIdx.x & 1;           // XCD parity: one dir per XCD
  const int word0 = (blockIdx.x >> 1) * MMW;
  const int j     = threadIdx.x;              // 0..1023 = 16 waves (4 per SIMD)
  const int wave  = j >> 6, lane = j & 63;
  const int quad  = lane >> 4, l15 = lane & 15;

  const bf16x8* pHH  = (const bf16x8*)(wsu + (size_t)dir*PK_HHD);
  const u16*    xpt  = wsu + XP_OFF_U16 + (size_t)dir*XPD;
  const float*  bias = (const float*)(wsu + BIAS_OFF_U16) + dir*1024;

  // this wave owns gate-tile nt == wave (16 output channels)
  const bf16x8* bHH = pHH + (size_t)(wave*3)*8*64 + lane;

  __shared__ __align__(16) u16 sh_hhi[MMW][HS];      // bf16 hi of h (16.9 KB)
  __shared__ __align__(16) u16 sh_hlo[MMW][HS];      // bf16 lo of h (16.9 KB)
  __shared__ __align__(16) u16 sh_xp[MMW][XPS];      // xp rows (50.4 KB)
  __shared__ __align__(16) int sh_cit[CC][MMW];      // chars, transposed (4 KB)
  __shared__ u32 sh_mb[MMW];                         // per-word step-mask bits

  const int sw = j >> 5, sp = j & 31;       // xp-staging: word (32), 24-u16 part (32)

  // ---- one-time staging ----
  {
    const int w = sw, c = sp;
    sh_cit[c][w] = __builtin_nontemporal_load(&chars[(word0 + w)*CC + c]);
    int mv = __builtin_nontemporal_load(&chars_mask[(word0 + w)*CC + c]);
    u64 bal = __ballot(mv != 0);            // lanes 0..31 -> word 2*wave, 32..63 -> 2*wave+1
    if (lane == 0) {
      sh_mb[2*wave]     = (u32)bal;
      sh_mb[2*wave + 1] = (u32)(bal >> 32);
    }
  }
  for (int i = j; i < MMW*HS/2; i += 1024) { ((float*)sh_hhi)[i] = 0.0f; ((float*)sh_hlo)[i] = 0.0f; }
  __syncthreads();                           // sh_mb / sh_cit visible

  const int ch = wave*16 + l15;             // this lane's output channel
  const float bR  = bias[ch],        bZ  = bias[256 + ch];
  const float bXN = bias[512 + ch],  bHN = bias[768 + ch];

  // per-lane owned words: word = m*16 + quad*4 + r
  u32 mb[2][4];
  float hreg[2][4];
  #pragma unroll
  for (int m = 0; m < 2; ++m)
    #pragma unroll
    for (int r = 0; r < 4; ++r) {
      mb[m][r] = sh_mb[m*16 + quad*4 + r];
      hreg[m][r] = 0.0f;
    }

  // 8 HH batches per step (kc 0..7), 3 frags each. FOUR buffer slots so the
  // rotation is step-aligned (8 % 4 == 0; 3 slots permuted kc across steps).
  bf16x8 buf[4][3];
  auto load_batch = [&](int kc, bf16x8 dst[3]) {
    #pragma unroll
    for (int g = 0; g < 3; ++g) dst[g] = bHH[(g*8 + kc)*64];
  };
  load_batch(0, buf[0]);
  load_batch(1, buf[1]);
  load_batch(2, buf[2]);

  #pragma unroll 1
  for (int s = 0; s < CC; ++s) {
    const int t = dir ? (CC - 1 - s) : s;
    __syncthreads();                                   // S0: h writes visible, prev xp reads done
    {
      int ci = sh_cit[t][sw];
      const uint4* src = (const uint4*)(xpt + (size_t)ci*768);   // 96 uint4 per row
      uint4 a0 = src[sp*3], a1 = src[sp*3+1], a2 = src[sp*3+2];
      *(uint4*)&sh_xp[sw][sp*24]      = a0;
      *(uint4*)&sh_xp[sw][sp*24 + 8]  = a1;
      *(uint4*)&sh_xp[sw][sp*24 + 16] = a2;
    }
    // (no S1: MFMA phase does not read sh_xp; S2 orders xp writes -> epilogue)

    // acc[0]=r, acc[1]=z, acc[2]=hn ; [m-tile]  (24 regs)
    f32x4 acc[3][2];
    #pragma unroll
    for (int m = 0; m < 2; ++m) {
      acc[0][m] = (f32x4){bR,bR,bR,bR};
      acc[1][m] = (f32x4){bZ,bZ,bZ,bZ};
      acc[2][m] = (f32x4){bHN,bHN,bHN,bHN};
    }

    // r,z gates: h_hi only (bounded, non-compounding error). n gate: exact hi+lo.
    auto mfma_batch = [&](int kc, bf16x8 src[3]) {
      #pragma unroll
      for (int m = 0; m < 2; ++m) {
        bf16x8 ah = *(const bf16x8*)&sh_hhi[m*16 + l15][kc*32 + quad*8];
        bf16x8 al = *(const bf16x8*)&sh_hlo[m*16 + l15][kc*32 + quad*8];
        acc[0][m] = __builtin_amdgcn_mfma_f32_16x16x32_bf16(ah, src[0], acc[0][m], 0,0,0);
        acc[1][m] = __builtin_amdgcn_mfma_f32_16x16x32_bf16(ah, src[1], acc[1][m], 0,0,0);
        acc[2][m] = __builtin_amdgcn_mfma_f32_16x16x32_bf16(ah, src[2], acc[2][m], 0,0,0);
        acc[2][m] = __builtin_amdgcn_mfma_f32_16x16x32_bf16(al, src[2], acc[2][m], 0,0,0);
      }
    };

    #pragma unroll
    for (int b = 0; b < 8; ++b) {
      mfma_batch(b, buf[b & 3]);
      load_batch((b + 3) & 7, buf[(b + 3) & 3]);       // b>=5 pre-issues next step's 0,1,2
    }

    __syncthreads();                                   // S2: h frag reads + xp writes done

    // ---- gate math + h update (lane owns (word, ch); h_old in regs) ----
    #pragma unroll
    for (int m = 0; m < 2; ++m)
      #pragma unroll
      for (int r = 0; r < 4; ++r) {
        const int word = m*16 + quad*4 + r;
        const u16* xrow = &sh_xp[word][0];
        float xr = bf2f(xrow[ch]);
        float xz = bf2f(xrow[256 + ch]);
        float xn = bf2f(xrow[512 + ch]);
        float rr = sigmoid_f(acc[0][m][r] + xr);
        float zz = sigmoid_f(acc[1][m][r] + xz);
        float nn = tanh_f(fmaf(rr, acc[2][m][r], bXN + xn));
        float hold = hreg[m][r];
        float hnew = fmaf(zz, hold - nn, nn);                  // (1-z)*n + z*h
        float cmf  = (float)((mb[m][r] >> t) & 1u);
        float hm   = fmaf(cmf, hnew - hold, hold);             // mask freeze
        hreg[m][r] = hm;
        u16 hi = f2bf(hm);
        sh_hhi[word][ch] = hi;
        sh_hlo[word][ch] = f2bf(hm - bf2f(hi));
      }
  }

  // ---- output straight from registers (owner mapping), nt stores ----
  #pragma unroll
  for (int m = 0; m < 2; ++m)
    #pragma unroll
    for (int r = 0; r < 4; ++r) {
      const int word = m*16 + quad*4 + r;
      float dm = (float)__builtin_nontemporal_load(&data_mask[word0 + word]);
      __builtin_nontemporal_store(hreg[m][r] * dm,
                                  &out[(size_t)(word0 + word)*(2*HHH) + dir*HHH + ch]);
    }
}

extern "C" void kernel_launch(void* const* d_in, const int* in_sizes, int n_in,
                              void* d_out, int out_size, void* d_ws, size_t ws_size,
                              hipStream_t stream) {
  const int*   chars      = (const int*)d_in[0];
  const int*   chars_mask = (const int*)d_in[1];
  const int*   data_mask  = (const int*)d_in[2];
  const float* embed      = (const float*)d_in[3];
  const float* Wih_fw     = (const float*)d_in[4];
  const float* Whh_fw     = (const float*)d_in[5];
  const float* bih_fw     = (const float*)d_in[6];
  const float* bhh_fw     = (const float*)d_in[7];
  const float* Wih_bw     = (const float*)d_in[8];
  const float* Whh_bw     = (const float*)d_in[9];
  const float* bih_bw     = (const float*)d_in[10];
  const float* bhh_bw     = (const float*)d_in[11];
  u16* wsu = (u16*)d_ws;

  prep_all<<<PREP_BLKS, 256, 0, stream>>>(embed, Wih_fw, Whh_fw, bih_fw, bhh_fw,
                                          Wih_bw, Whh_bw, bih_bw, bhh_bw, wsu);

  // 256 blocks: (word-group, dir) packed so dir == blockIdx&1 (XCD parity)
  gru_mfma<<<(NWORDS/MMW)*2, 1024, 0, stream>>>(chars, chars_mask, data_mask, wsu, (float*)d_out);
}

// Round 8
// 357.063 us; speedup vs baseline: 2.3894x; 1.1665x over previous
//
#include <hip/hip_runtime.h>
#include <hip/hip_bf16.h>

typedef unsigned int u32;
typedef unsigned short u16;
typedef __attribute__((ext_vector_type(8))) short bf16x8;
typedef __attribute__((ext_vector_type(4))) float f32x4;

// Problem constants
#define NWORDS 4096   // B*S
#define CC 32         // chars per word
#define EE 128        // embed dim
#define HHH 256       // hidden
#define MMW 32        // words per block (2 m-tiles per wave)
#define VOCABN 262

// LDS row strides
#define HS 264        // u16 stride for h arrays (fastest measured, R15/R18)
#define XPS 788       // u16 stride for xp rows. SINGLE CHANGE vs champion:
                      // 784 -> 788. Epilogue reads word*XPS+ch had 4-word quad
                      // stride 1568 dw == 0 mod 32 banks -> 4-way conflict on
                      // 24 reads/lane/step. 788: stride 1576 dw == 8 mod 32 ->
                      // quads tile all 32 banks -> conflict-free. Staging
                      // writes (sp*24+{0,8,16} <= 784) unaffected.

// Workspace layout (u16 units):
//   HH pack per dir: frag[(nt*3+g)*8+kc][lane][8] -> 16*3*8*512 = 196608 u16 (bf16 hi of Whh)
//   XP table per dir: [262][768] bf16 = embed @ Wih^T (no bias)
//   bias: per dir 1024 f32: [0..511]=bih+bhh(r,z); [512..767]=bih_n; [768..1023]=bhh_n
#define PK_HHD (16*3*8*512)                  // 196608
#define XP_OFF_U16 (2*PK_HHD)                // 393216
#define XPD (VOCABN*768)                     // 201216
#define BIAS_OFF_U16 (XP_OFF_U16 + 2*XPD)    // 795648 (byte 1591296, 4-aligned)

// fused-prep grid split
#define XP_NCH 8
#define XP_CBLK ((VOCABN + XP_NCH - 1) / XP_NCH)      // 33
#define PREP_PACK_BLKS (2*PK_HHD/256)                 // 1536
#define PREP_XP_BLKS (XP_CBLK*2)                      // 66
#define PREP_BLKS (PREP_PACK_BLKS + PREP_XP_BLKS + 1) // 1603

__device__ __forceinline__ float bf2f(u16 u){ union{u32 i; float f;} v; v.i=((u32)u)<<16; return v.f; }
__device__ __forceinline__ u16 f2bf(float f){
  __hip_bfloat16 h = __float2bfloat16(f);   // rne
  u16 r; __builtin_memcpy(&r, &h, 2); return r;
}
__device__ __forceinline__ float sigmoid_f(float x){
  float e = __builtin_amdgcn_exp2f(-1.4426950408889634f * x);
  return __builtin_amdgcn_rcpf(1.0f + e);
}
__device__ __forceinline__ float tanh_f(float x){
  float ax = __builtin_fabsf(x);
  float e  = __builtin_amdgcn_exp2f(-2.8853900817779268f * ax);
  float t  = 1.0f - 2.0f * e * __builtin_amdgcn_rcpf(1.0f + e);
  return __builtin_copysignf(t, x);
}

// ---- fused prep: Whh pack + tiled XP table + biases, one launch (R15) ----
__global__ void prep_all(const float* __restrict__ emb,
                         const float* __restrict__ Wih_fw, const float* __restrict__ Whh_fw,
                         const float* __restrict__ bih_fw, const float* __restrict__ bhh_fw,
                         const float* __restrict__ Wih_bw, const float* __restrict__ Whh_bw,
                         const float* __restrict__ bih_bw, const float* __restrict__ bhh_bw,
                         u16* __restrict__ wsu)
{
  const int bid = blockIdx.x, tid = threadIdx.x;
  if (bid < PREP_PACK_BLKS) {
    // -------- Whh pack (bf16 hi only) --------
    int idx = bid*256 + tid;                  // 2*PK_HHD elements
    int d = idx / PK_HHD;
    int e = idx - d*PK_HHD;
    const float* Whh = d ? Whh_bw : Whh_fw;
    int jj   = e & 7;
    int lane = (e >> 3) & 63;
    int kc   = (e >> 9) & 7;
    int gnt  = e >> 12;                       // nt*3+g, < 48
    int g = gnt % 3, nt = gnt / 3;
    int row = g*256 + nt*16 + (lane & 15);
    int k   = kc*32 + ((lane >> 4) << 3) + jj;
    wsu[idx] = f2bf(Whh[row*HHH + k]);
  } else if (bid < PREP_PACK_BLKS + PREP_XP_BLKS) {
    // -------- XP table, tiled: block = (8 chars x dir), embed rows in LDS --------
    const int b    = bid - PREP_PACK_BLKS;
    const int dirb = b & 1;
    const int c0   = (b >> 1) * XP_NCH;
    const float* Wih = dirb ? Wih_bw : Wih_fw;
    u16* xpo = wsu + XP_OFF_U16 + (size_t)dirb*XPD;

    __shared__ float sh_E[XP_NCH][EE];        // 4 KB
    for (int i = tid; i < XP_NCH*EE; i += 256) {
      int c = c0 + i/EE;
      sh_E[0][i] = (c < VOCABN) ? emb[(size_t)c*EE + (i & (EE-1))] : 0.0f;
    }
    __syncthreads();

    #pragma unroll 1
    for (int q = 0; q < 3; ++q) {             // gate channel g = q*256 + tid
      const int g = q*256 + tid;
      const float* W = Wih + (size_t)g*EE;
      float acc[XP_NCH];
      #pragma unroll
      for (int c = 0; c < XP_NCH; ++c) acc[c] = 0.0f;
      #pragma unroll 2
      for (int k = 0; k < EE; k += 4) {
        float4 wv = *(const float4*)(W + k);
        #pragma unroll
        for (int c = 0; c < XP_NCH; ++c) {
          float4 ev = *(const float4*)(&sh_E[c][k]);
          acc[c] = fmaf(ev.w, wv.w, fmaf(ev.z, wv.z, fmaf(ev.y, wv.y, fmaf(ev.x, wv.x, acc[c]))));
        }
      }
      #pragma unroll
      for (int c = 0; c < XP_NCH; ++c) {
        int ci = c0 + c;
        if (ci < VOCABN) xpo[(size_t)ci*768 + g] = f2bf(acc[c]);
      }
    }
  } else {
    // -------- biases (one block handles all 2048, 8 per thread) --------
    #pragma unroll
    for (int rep = 0; rep < 8; ++rep) {
      int i = rep*256 + tid;
      int d = i >> 10, o = i & 1023;
      const float* bih = d ? bih_bw : bih_fw;
      const float* bhh = d ? bhh_bw : bhh_fw;
      float v;
      if (o < 512)      v = bih[o] + bhh[o];
      else if (o < 768) v = bih[o - 512 + 512];   // bih_n
      else              v = bhh[o - 768 + 512];   // bhh_n
      ((float*)(wsu + BIAS_OFF_U16))[d*1024 + o] = v;
    }
  }
}

// ==== R18 measured-best gru kernel (291.5 us dispatch), restored verbatim,
// with ONE variable changed: XPS 784 -> 788 (epilogue xp-read bank conflicts).
// 2 barriers/step: sh_xp written in staging, read only in epilogue (after S2);
// MFMA phase never touches it. Cooperative uint4 gather -> LDS beats per-lane
// scalar gather (R19: fewer bytes/conflicts but worse time -- issue-rate and
// vmcnt-drain shape dominate).
__global__ __launch_bounds__(1024)
void gru_mfma(const int* __restrict__ chars, const int* __restrict__ chars_mask,
              const int* __restrict__ data_mask, const u16* __restrict__ wsu,
              float* __restrict__ out)
{
  const int dir   = blockIdx.x & 1;           // XCD parity: one dir per XCD
  const int word0 = (blockIdx.x >> 1) * MMW;
  const int j     = threadIdx.x;              // 0..1023 = 16 waves (4 per SIMD)
  const int wave  = j >> 6, lane = j & 63;
  const int quad  = lane >> 4, l15 = lane & 15;

  const bf16x8* pHH  = (const bf16x8*)(wsu + (size_t)dir*PK_HHD);
  const u16*    xpt  = wsu + XP_OFF_U16 + (size_t)dir*XPD;
  const float*  bias = (const float*)(wsu + BIAS_OFF_U16) + dir*1024;

  // this wave owns gate-tile nt == wave (16 output channels)
  const bf16x8* bHH = pHH + (size_t)(wave*3)*8*64 + lane;

  __shared__ __align__(16) u16   sh_hhi[MMW][HS];     // bf16 hi of h, A-layout (16.9 KB)
  __shared__ __align__(16) u16   sh_hlo[MMW][HS];     // bf16 lo of h           (16.9 KB)
  __shared__ __align__(16) u16   sh_xp[MMW][XPS];     // xp rows (768 used)     (50.4 KB)
  __shared__ int   sh_ci[MMW][CC + 1];                // chars block            (4.2 KB)
  __shared__ float sh_cm[MMW][CC + 1];                // chars_mask block       (4.2 KB)

  // ---- one-time staging: chars/mask (1024 threads == MMW*CC), zero h ----
  {
    const int w = j >> 5, c = j & 31;
    sh_ci[w][c] = chars[(word0 + w)*CC + c];
    sh_cm[w][c] = (float)chars_mask[(word0 + w)*CC + c];
  }
  for (int i = j; i < MMW*HS/2; i += 1024) { ((float*)sh_hhi)[i] = 0.0f; ((float*)sh_hlo)[i] = 0.0f; }

  const int ch = wave*16 + l15;             // this lane's output channel
  const float bR  = bias[ch],        bZ  = bias[256 + ch];
  const float bXN = bias[512 + ch],  bHN = bias[768 + ch];

  const int sw = j >> 5, sp = j & 31;       // xp-staging: word (32), 24-u16 part (32)

  // 8 HH batches per step (kc 0..7), 3 frags each. FOUR buffer slots so the
  // rotation is step-aligned (8 % 4 == 0; 3 slots permuted kc across steps).
  bf16x8 buf[4][3];
  auto load_batch = [&](int kc, bf16x8 dst[3]) {
    #pragma unroll
    for (int g = 0; g < 3; ++g) dst[g] = bHH[(g*8 + kc)*64];
  };
  load_batch(0, buf[0]);
  load_batch(1, buf[1]);
  load_batch(2, buf[2]);

  #pragma unroll 1
  for (int s = 0; s < CC; ++s) {
    const int t = dir ? (CC - 1 - s) : s;
    __syncthreads();                                   // S0: h writes visible, prev xp reads done
    {
      int ci = sh_ci[sw][t];
      const uint4* src = (const uint4*)(xpt + (size_t)ci*768);   // 96 uint4 per row
      uint4 a0 = src[sp*3], a1 = src[sp*3+1], a2 = src[sp*3+2];
      *(uint4*)&sh_xp[sw][sp*24]      = a0;
      *(uint4*)&sh_xp[sw][sp*24 + 8]  = a1;
      *(uint4*)&sh_xp[sw][sp*24 + 16] = a2;
    }
    // (no S1: MFMA phase does not read sh_xp; S2 orders xp writes -> epilogue)

    // acc[0]=r, acc[1]=z, acc[2]=hn ; [m-tile]  (24 regs)
    f32x4 acc[3][2];
    #pragma unroll
    for (int m = 0; m < 2; ++m) {
      acc[0][m] = (f32x4){bR,bR,bR,bR};
      acc[1][m] = (f32x4){bZ,bZ,bZ,bZ};
      acc[2][m] = (f32x4){bHN,bHN,bHN,bHN};
    }

    // r,z gates: h_hi only (bounded, non-compounding error). n gate: exact hi+lo.
    auto mfma_batch = [&](int kc, bf16x8 src[3]) {
      #pragma unroll
      for (int m = 0; m < 2; ++m) {
        bf16x8 ah = *(const bf16x8*)&sh_hhi[m*16 + l15][kc*32 + quad*8];
        bf16x8 al = *(const bf16x8*)&sh_hlo[m*16 + l15][kc*32 + quad*8];
        acc[0][m] = __builtin_amdgcn_mfma_f32_16x16x32_bf16(ah, src[0], acc[0][m], 0,0,0);
        acc[1][m] = __builtin_amdgcn_mfma_f32_16x16x32_bf16(ah, src[1], acc[1][m], 0,0,0);
        acc[2][m] = __builtin_amdgcn_mfma_f32_16x16x32_bf16(ah, src[2], acc[2][m], 0,0,0);
        acc[2][m] = __builtin_amdgcn_mfma_f32_16x16x32_bf16(al, src[2], acc[2][m], 0,0,0);
      }
    };

    #pragma unroll
    for (int b = 0; b < 8; ++b) {
      mfma_batch(b, buf[b & 3]);
      load_batch((b + 3) & 7, buf[(b + 3) & 3]);       // b>=5 pre-issues next step's 0,1,2
    }

    __syncthreads();                                   // S2: h frag reads + xp writes done

    // ---- gate math + h update (lane owns (word, ch) pairs) ----
    #pragma unroll
    for (int m = 0; m < 2; ++m)
      #pragma unroll
      for (int r = 0; r < 4; ++r) {
        const int word = m*16 + quad*4 + r;
        float xr = bf2f(sh_xp[word][ch]);
        float xz = bf2f(sh_xp[word][256 + ch]);
        float xn = bf2f(sh_xp[word][512 + ch]);
        float rr = sigmoid_f(acc[0][m][r] + xr);
        float zz = sigmoid_f(acc[1][m][r] + xz);
        float nn = tanh_f(fmaf(rr, acc[2][m][r], bXN + xn));
        float hold = bf2f(sh_hhi[word][ch]) + bf2f(sh_hlo[word][ch]);
        float hnew = fmaf(zz, hold - nn, nn);                  // (1-z)*n + z*h
        float hm   = fmaf(sh_cm[word][t], hnew - hold, hold);  // mask freeze
        u16 hi = f2bf(hm);
        sh_hhi[word][ch] = hi;
        sh_hlo[word][ch] = f2bf(hm - bf2f(hi));
      }
  }
  __syncthreads();

  // ---- output: 32 words x 256 ch, coalesced fp32 ----
  const int oc = j & 255, og = j >> 8;     // 4 groups of 8 words
  #pragma unroll
  for (int i = 0; i < 8; ++i) {
    const int w = og*8 + i;
    float dm = (float)data_mask[word0 + w];
    float h = bf2f(sh_hhi[w][oc]) + bf2f(sh_hlo[w][oc]);
    out[(size_t)(word0 + w)*(2*HHH) + dir*HHH + oc] = h * dm;
  }
}

extern "C" void kernel_launch(void* const* d_in, const int* in_sizes, int n_in,
                              void* d_out, int out_size, void* d_ws, size_t ws_size,
                              hipStream_t stream) {
  const int*   chars      = (const int*)d_in[0];
  const int*   chars_mask = (const int*)d_in[1];
  const int*   data_mask  = (const int*)d_in[2];
  const float* embed      = (const float*)d_in[3];
  const float* Wih_fw     = (const float*)d_in[4];
  const float* Whh_fw     = (const float*)d_in[5];
  const float* bih_fw     = (const float*)d_in[6];
  const float* bhh_fw     = (const float*)d_in[7];
  const float* Wih_bw     = (const float*)d_in[8];
  const float* Whh_bw     = (const float*)d_in[9];
  const float* bih_bw     = (const float*)d_in[10];
  const float* bhh_bw     = (const float*)d_in[11];
  u16* wsu = (u16*)d_ws;

  prep_all<<<PREP_BLKS, 256, 0, stream>>>(embed, Wih_fw, Whh_fw, bih_fw, bhh_fw,
                                          Wih_bw, Whh_bw, bih_bw, bhh_bw, wsu);

  // 256 blocks: (word-group, dir) packed so dir == blockIdx&1 (XCD parity)
  gru_mfma<<<(NWORDS/MMW)*2, 1024, 0, stream>>>(chars, chars_mask, data_mask, wsu, (float*)d_out);
}